// Round 15
// baseline (185.668 us; speedup 1.0000x reference)
//
#include <hip/hip_runtime.h>
#include <math.h>

typedef unsigned short u16;
typedef unsigned int u32;
typedef __attribute__((ext_vector_type(4))) float f32x4;
typedef __attribute__((ext_vector_type(8))) short s16x8;

#define GLL16(g, l) __builtin_amdgcn_global_load_lds( \
    (const __attribute__((address_space(1))) void*)(g), \
    (__attribute__((address_space(3))) void*)(l), 16, 0, 0)

#define MFMA16(a, b, c) __builtin_amdgcn_mfma_f32_16x16x32_bf16(a, b, c, 0, 0, 0)

__device__ __forceinline__ u16 f2bf(float f) {
  union { float f; u32 u; } v; v.f = f;
  u32 r = v.u + 0x7FFFu + ((v.u >> 16) & 1u);
  return (u16)(r >> 16);
}
__device__ __forceinline__ float bf2f(u16 h) {
  union { u32 u; float f; } v; v.u = ((u32)h) << 16;
  return v.f;
}
// pack two floats to bf16x2 (round-half-up) in one v_perm
__device__ __forceinline__ u32 pk2bf(float lo, float hi) {
  union { float f; u32 u; } a, b; a.f = lo; b.f = hi;
  return __builtin_amdgcn_perm(b.u + 0x8000u, a.u + 0x8000u, 0x07060302u);
}
__device__ __forceinline__ float fexp2(float x) {
#if __has_builtin(__builtin_amdgcn_exp2f)
  return __builtin_amdgcn_exp2f(x);
#else
  return exp2f(x);
#endif
}
// hardware sin/cos on pre-reduced revolutions (r in [0,1)); register-only,
// no library call, no scratch (R9 post-mortem: ocml sincosf spilled ~200 MB).
__device__ __forceinline__ float fsin_rev(float r) {
#if __has_builtin(__builtin_amdgcn_sinf)
  return __builtin_amdgcn_sinf(r);
#else
  return __sinf(r * 6.283185307179586f);
#endif
}
__device__ __forceinline__ float fcos_rev(float r) {
#if __has_builtin(__builtin_amdgcn_cosf)
  return __builtin_amdgcn_cosf(r);
#else
  return __cosf(r * 6.283185307179586f);
#endif
}

// ---------------- fused prep: rmsnorm + both weight casts (1 launch) ----------
__global__ __launch_bounds__(256) void prep_kernel(const float* __restrict__ x,
                                                   const float* __restrict__ wgt,
                                                   const float* __restrict__ w_qkv,
                                                   const float* __restrict__ w_out,
                                                   u16* __restrict__ h,
                                                   u16* __restrict__ wqkv_b,
                                                   u16* __restrict__ wout_b) {
  __shared__ float red[4];
  const int bid = blockIdx.x, tid = threadIdx.x;
  if (bid < 4096) {
    // RMSNorm row
    const int row = bid;
    const float4 v = *(const float4*)&x[(size_t)row * 1024 + tid * 4];
    float ss = v.x * v.x + v.y * v.y + v.z * v.z + v.w * v.w;
    ss += __shfl_xor(ss, 1);  ss += __shfl_xor(ss, 2);  ss += __shfl_xor(ss, 4);
    ss += __shfl_xor(ss, 8);  ss += __shfl_xor(ss, 16); ss += __shfl_xor(ss, 32);
    if ((tid & 63) == 0) red[tid >> 6] = ss;
    __syncthreads();
    const float tot = red[0] + red[1] + red[2] + red[3];
    const float s = rsqrtf(tot * (1.0f / 1024.0f) + 1e-6f);
    const float4 g = *(const float4*)&wgt[tid * 4];
    uint2 o;
    o.x = (u32)f2bf(v.x * s * g.x) | ((u32)f2bf(v.y * s * g.y) << 16);
    o.y = (u32)f2bf(v.z * s * g.z) | ((u32)f2bf(v.w * s * g.w) << 16);
    *(uint2*)&h[(size_t)row * 1024 + tid * 4] = o;
  } else if (bid < 7168) {
    int i = (bid - 4096) * 256 + tid;          // 786432 float4 of w_qkv
    float4 v = ((const float4*)w_qkv)[i];
    uint2 o;
    o.x = (u32)f2bf(v.x) | ((u32)f2bf(v.y) << 16);
    o.y = (u32)f2bf(v.z) | ((u32)f2bf(v.w) << 16);
    ((uint2*)wqkv_b)[i] = o;
  } else {
    int i = (bid - 7168) * 256 + tid;          // 262144 float4 of w_out
    float4 v = ((const float4*)w_out)[i];
    uint2 o;
    o.x = (u32)f2bf(v.x) | ((u32)f2bf(v.y) << 16);
    o.y = (u32)f2bf(v.z) | ((u32)f2bf(v.w) << 16);
    ((uint2*)wout_b)[i] = o;
  }
}

// ---------------- GEMM 128^2 (kept for out-proj): C = A * Bt^T ----------------
template <int EPI>  // 0: write bf16 C. 1: write fp32 C = acc + resid
__global__ __launch_bounds__(256) void gemm_bt(const u16* __restrict__ A,
                                               const u16* __restrict__ Bt,
                                               u16* __restrict__ Cb,
                                               float* __restrict__ Cf,
                                               const float* __restrict__ resid,
                                               int M, int N, int K) {
  __shared__ __attribute__((aligned(16))) u16 As[128 * 32];
  __shared__ __attribute__((aligned(16))) u16 Bs[128 * 32];
  const int tid = threadIdx.x;
  const int w = tid >> 6, lane = tid & 63;
  const int quad = lane >> 4, l16 = lane & 15;
  const int gm0 = blockIdx.y * 128, gn0 = blockIdx.x * 128;
  const int wm = (w & 1) * 64, wn = (w >> 1) * 64;

  f32x4 acc[4][4] = {};

  for (int k0 = 0; k0 < K; k0 += 32) {
    __syncthreads();
    if (w < 2) {
      #pragma unroll
      for (int i = 0; i < 4; ++i) {
        int sb = (w * 4 + i) * 64;
        int slot = sb + lane;
        int m = slot >> 2, c = (slot & 3) ^ (m & 3);
        GLL16(A + (size_t)(gm0 + m) * K + k0 + c * 8, &As[sb * 8]);
      }
    } else {
      #pragma unroll
      for (int i = 0; i < 4; ++i) {
        int sb = ((w - 2) * 4 + i) * 64;
        int slot = sb + lane;
        int n = slot >> 2, c = (slot & 3) ^ (n & 3);
        GLL16(Bt + (size_t)(gn0 + n) * K + k0 + c * 8, &Bs[sb * 8]);
      }
    }
    __syncthreads();
    s16x8 aF[4], bF[4];
    #pragma unroll
    for (int i = 0; i < 4; ++i) {
      int m = wm + i * 16 + l16;
      aF[i] = *(const s16x8*)&As[(m * 4 + (quad ^ (m & 3))) * 8];
    }
    #pragma unroll
    for (int j = 0; j < 4; ++j) {
      int n = wn + j * 16 + l16;
      bF[j] = *(const s16x8*)&Bs[(n * 4 + (quad ^ (n & 3))) * 8];
    }
    #pragma unroll
    for (int i = 0; i < 4; ++i)
      #pragma unroll
      for (int j = 0; j < 4; ++j)
        acc[i][j] = MFMA16(aF[i], bF[j], acc[i][j]);
  }

  #pragma unroll
  for (int i = 0; i < 4; ++i) {
    int row0 = gm0 + wm + i * 16 + quad * 4;
    #pragma unroll
    for (int j = 0; j < 4; ++j) {
      int col = gn0 + wn + j * 16 + l16;
      #pragma unroll
      for (int r = 0; r < 4; ++r) {
        size_t idx = (size_t)(row0 + r) * N + col;
        if (EPI == 0) Cb[idx] = f2bf(acc[i][j][r]);
        else          Cf[idx] = acc[i][j][r] + resid[idx];
      }
    }
  }
}

// ---------------- GEMM 256^2 v3b: QKV matmul + fused RoPE/V-transpose ---------
// (R11/R14 best configuration, passing at ~43 us incl. fused epilogue)
__global__ __launch_bounds__(512, 2) void gemm256(const u16* __restrict__ A,
                                                  const u16* __restrict__ Bt,
                                                  u16* __restrict__ Qr,
                                                  u16* __restrict__ Kr,
                                                  u16* __restrict__ Vt) {
  __shared__ __attribute__((aligned(16))) char smem[131072];
  const int tid = threadIdx.x;
  const int w = tid >> 6, lane = tid & 63;
  const int quad = lane >> 4, l16 = lane & 15;
  const int wr = w >> 2, wc = w & 3;
  const int rsw = l16 & 7;
  const int id = blockIdx.x;
  const int sw = (id & 7) * 24 + (id >> 3);    // XCD swizzle, 192 = 8 x 24
  const int by = sw / 12, bx = sw - by * 12;
  const int gm0 = by * 256, gn0 = bx * 256;
  const int scg = (lane & 7) ^ (lane >> 3);    // pre-swizzled src col-group

  // part: 0=A half0, 1=A half1, 2=B half0, 3=B half1 (half = 128 rows)
  auto STAGE_HALF = [&](int kt, int part) {
    const int sb = (kt & 1) * 65536 + (part >> 1) * 32768 + (part & 1) * 16384;
    const u16* src = (part >> 1) ? Bt : A;
    const int g0 = ((part >> 1) ? gn0 : gm0) + (part & 1) * 128;
    const int k0 = kt * 64;
    #pragma unroll
    for (int q = 0; q < 2; ++q) {
      int r = q * 64 + (tid >> 3);
      GLL16(src + (size_t)(g0 + r) * 1024 + k0 + scg * 8,
            smem + sb + q * 8192 + w * 1024);
    }
  };

  f32x4 acc[8][4] = {};

  // prologue: A(0), B(0), B(1).  vmcnt(4): A(0)+B(0) landed, B(1) in flight.
  STAGE_HALF(0, 0); STAGE_HALF(0, 1);
  STAGE_HALF(0, 2); STAGE_HALF(0, 3);
  STAGE_HALF(1, 2); STAGE_HALF(1, 3);
  asm volatile("s_waitcnt vmcnt(4)" ::: "memory");
  __builtin_amdgcn_s_barrier();

  for (int kt = 0; kt < 16; ++kt) {
    const char* Ab = smem + (kt & 1) * 65536;
    const char* Bb = Ab + 32768;
    const int arow = wr * 128 + l16;            // (row&7)==rsw for all frags
    const int brow = wc * 64 + l16;
    s16x8 aA[4][2], bB[4][2];

    // reads: A row-group 0 (8 x b128) + all B (8 x b128)
    #pragma unroll
    for (int fi = 0; fi < 4; ++fi) {
      const char* p = Ab + (arow + fi * 16) * 128;
      aA[fi][0] = *(const s16x8*)(p + ((quad ^ rsw) * 16));
      aA[fi][1] = *(const s16x8*)(p + (((4 + quad) ^ rsw) * 16));
    }
    #pragma unroll
    for (int fj = 0; fj < 4; ++fj) {
      const char* p = Bb + (brow + fj * 16) * 128;
      bB[fj][0] = *(const s16x8*)(p + ((quad ^ rsw) * 16));
      bB[fj][1] = *(const s16x8*)(p + (((4 + quad) ^ rsw) * 16));
    }

    // stage A(kt+1) into the other buffer (its previous content consumed @ kt-1)
    if (kt < 15) { STAGE_HALF(kt + 1, 0); STAGE_HALF(kt + 1, 1); }

    // MFMA row-group 0 x all cols (32) - compiler interleaves lgkmcnt waits
    __builtin_amdgcn_s_setprio(1);
    #pragma unroll
    for (int fi = 0; fi < 4; ++fi)
      #pragma unroll
      for (int fj = 0; fj < 4; ++fj) {
        acc[fi][fj] = MFMA16(aA[fi][0], bB[fj][0], acc[fi][fj]);
        acc[fi][fj] = MFMA16(aA[fi][1], bB[fj][1], acc[fi][fj]);
      }
    __builtin_amdgcn_s_setprio(0);

    // reads: A row-group 1 (8 x b128) - drains under rg0 MFMA execution
    #pragma unroll
    for (int fi = 0; fi < 4; ++fi) {
      const char* p = Ab + (arow + (4 + fi) * 16) * 128;
      aA[fi][0] = *(const s16x8*)(p + ((quad ^ rsw) * 16));
      aA[fi][1] = *(const s16x8*)(p + (((4 + quad) ^ rsw) * 16));
    }

    // MFMA row-group 1 x all cols (32)
    __builtin_amdgcn_s_setprio(1);
    #pragma unroll
    for (int fi = 0; fi < 4; ++fi)
      #pragma unroll
      for (int fj = 0; fj < 4; ++fj) {
        acc[4 + fi][fj] = MFMA16(aA[fi][0], bB[fj][0], acc[4 + fi][fj]);
        acc[4 + fi][fj] = MFMA16(aA[fi][1], bB[fj][1], acc[4 + fi][fj]);
      }
    __builtin_amdgcn_s_setprio(0);

    // all waves' reads of buf[kt&1] complete (consumed by MFMAs above)
    __builtin_amdgcn_s_barrier();

    // stage B(kt+2) into buf[kt&1] B-region (now dead)
    if (kt < 14) {
      STAGE_HALF(kt + 2, 2); STAGE_HALF(kt + 2, 3);
      asm volatile("s_waitcnt vmcnt(4)" ::: "memory");   // A(kt+1),B(kt+1) landed
    } else if (kt == 14) {
      asm volatile("s_waitcnt vmcnt(0)" ::: "memory");   // A(15) landed
    }
    __builtin_amdgcn_s_barrier();
  }

  // ---- fused epilogue: RoPE (Q/K) or transpose (V), direct to final layout --
  const int bb = gm0 >> 11;                    // batch (rows are 2048-aligned blocks)
  const int tt0 = (gm0 & 2047) + wr * 128;     // this wave's first token
  if (bx < 8) {
    const bool isQ = (bx < 4);
    const int h = ((bx & 3) << 2) + wc;        // head index 0..15
    const size_t obase = (size_t)(bb * 16 + h) * (2048 * 64);
    u16* dst = isQ ? Qr : Kr;
    const float SC = isQ ? 0.125f * 1.4426950408889634f : 1.0f;
    #pragma unroll
    for (int fj = 0; fj < 2; ++fj) {
      const int jj = fj * 16 + l16;            // rotation pair index 0..31
      // invf/(2*pi): angle in revolutions, fract-reduce, hardware sin/cos
      const float invf_rev = fexp2(-(float)jj * (13.287712379549449f / 32.0f)) *
                             0.15915494309189535f;
      #pragma unroll
      for (int g = 0; g < 8; ++g) {
        #pragma unroll
        for (int r = 0; r < 4; ++r) {
          const int t = tt0 + g * 16 + quad * 4 + r;
          const float rev = (float)t * invf_rev;
          const float fr = rev - floorf(rev);
          const float sn = fsin_rev(fr), cs = fcos_rev(fr);
          const float q1 = acc[g][fj][r], q2 = acc[g][2 + fj][r];
          dst[obase + (size_t)t * 64 + jj]      = f2bf((q1 * cs - q2 * sn) * SC);
          dst[obase + (size_t)t * 64 + jj + 32] = f2bf((q2 * cs + q1 * sn) * SC);
        }
      }
    }
  } else {
    // V: per-wave head, transpose 256x64 through LDS (32 KB per head, 4 heads
    // = exactly the 128 KB smem, dead after the K-loop's final barrier).
    const int h = ((bx - 8) << 2) + wc;
    const size_t obase = (size_t)(bb * 16 + h) * 64;   // Vt row base (bh*64)
    u16* Vl = (u16*)smem + wc * 16384;
    #pragma unroll
    for (int g = 0; g < 8; ++g)
      #pragma unroll
      for (int fj = 0; fj < 4; ++fj) {
        const int d = fj * 16 + l16;
        #pragma unroll
        for (int r = 0; r < 4; ++r) {
          const int tl = wr * 128 + g * 16 + quad * 4 + r;
          Vl[tl * 64 + (d ^ (((tl >> 3) & 7) << 3))] = f2bf(acc[g][fj][r]);
        }
      }
    __syncthreads();   // uniform within block (bx is block-constant)
    const int c = lane & 7, lg = lane >> 3;
    const int tb = gm0 & 2047;
    #pragma unroll
    for (int c32 = wr * 2; c32 < wr * 2 + 2; ++c32)
      #pragma unroll
      for (int dp = 0; dp < 8; ++dp) {
        const int d = dp * 8 + lg;
        const u16* col = Vl + (c32 * 64 + c * 8) * 64 + (d ^ (c << 3));
        u16 tmp[8];
        #pragma unroll
        for (int k = 0; k < 8; ++k) tmp[k] = col[k * 64];
        *(uint4*)&Vt[(obase + d) * 2048 + tb + c32 * 64 + c * 8] = *(uint4*)tmp;
      }
  }
}

// ---------------- Flash attention v10b: 80 KB LDS, NATURAL register alloc ----
// R13's v10 structure (verified correct) failed only because (512,4) forced
// VGPR to the 64 step -> 300 MB spill. R15: plain __launch_bounds__(512) -
// natural allocation for this body is ~100-112 VGPR (R7 measured 100), under
// the 128 ceiling for 4 waves/SIMD, so LDS (80 KB) becomes the occupancy
// limiter at exactly 2 blocks/CU. Cross-block overlap (proven in R12's v9)
// plus the prefetched parity k-split body. Grid 512, adjacent-id
// complementarity: id=2k -> (bh=k&31, qblk=k>>5), id=2k+1 -> (bh, 15-qblk).
__global__ __launch_bounds__(512) void attn_kernel(const u16* __restrict__ Qr,
                                                   const u16* __restrict__ Kr,
                                                   const u16* __restrict__ Vt,
                                                   u16* __restrict__ AO) {
  // [0,32K): K[par*2+d][8192]  [32K,64K): V[par*2+d][8192]  [64K,80K): P[8][2048]
  __shared__ __attribute__((aligned(16))) char smem[81920];
  const int tid = threadIdx.x;
  const int w = tid >> 6, lane = tid & 63;
  const int wq = w & 3, wp = w >> 2;          // compute roles: q-quarter, j-parity
  const int quad = lane >> 4, l16 = lane & 15;
  const int id = blockIdx.x;
  const int kk = id >> 1, odd = id & 1;
  const int bh = kk & 31;                     // adjacent ids share bh (L2 reuse)
  const int qh = kk >> 5;                     // 0..7
  const int qblk = odd ? (15 - qh) : qh;      // adjacent ids are complementary
  const int b = bh >> 4, h = bh & 15;
  const size_t qkb = (size_t)bh * (2048 * 64);
  const size_t vtb = (size_t)bh * (64 * 2048);
  char* PwB = smem + 65536 + w * 2048;

  const int srow = lane >> 3;                 // row within an 8-row issue
  const int scg  = (lane & 7) ^ srow;         // pre-swizzled 16B col group
  const int smat = w & 1, stp = (w >> 1) & 1, shalf = (w >> 2) & 1;

  auto STAGE = [&](int j0, int d) {
    const int jn = j0 + stp;
    if (smat == 0) {
      #pragma unroll
      for (int ii = 0; ii < 4; ++ii) {
        int i = shalf * 4 + ii;               // 8-row block 0..7
        GLL16(Kr + qkb + (size_t)(jn * 64 + i * 8 + srow) * 64 + scg * 8,
              smem + (stp * 2 + d) * 8192 + i * 1024);
      }
    } else {
      #pragma unroll
      for (int ii = 0; ii < 4; ++ii) {
        int i = shalf * 4 + ii;               // 8 d-rows each
        GLL16(Vt + vtb + (size_t)(i * 8 + srow) * 2048 + jn * 64 + scg * 8,
              smem + 32768 + (stp * 2 + d) * 8192 + i * 1024);
      }
    }
  };

  const int q0w = qblk * 128 + wq * 32;       // this wave's 32 q-rows
  const int steps = qblk + 1;                 // j-tiles = 2*steps

  s16x8 bQ[2][2];
  #pragma unroll
  for (int s = 0; s < 2; ++s)
    #pragma unroll
    for (int hf = 0; hf < 2; ++hf)
      bQ[s][hf] = *(const s16x8*)&Qr[qkb + (size_t)(q0w + s * 16 + l16) * 64 + hf * 32 + quad * 8];

  f32x4 O[2][4] = {};
  float l_run[2] = {0.0f, 0.0f};

  STAGE(0, 0);
  __syncthreads();   // compiler drains vmcnt before s_barrier -> dbuf0 ready

  for (int st = 0; st < steps; ++st) {
    const int cur = st & 1;
    if (st + 1 < steps) STAGE(2 * st + 2, cur ^ 1);   // prefetch next pair

    const int j = 2 * st + wp;                // this wave's j-tile
    if (j * 64 <= q0w + 31) {                 // wave-uniform skip of masked tiles
      const u16* Kb = (const u16*)(smem + (wp * 2 + cur) * 8192);
      const u16* Vb = (const u16*)(smem + 32768 + (wp * 2 + cur) * 8192);
      const bool masked = (j * 64 + 63 > q0w);
      const int rsw = (l16 & 7);

      s16x8 aK[4][2];
      #pragma unroll
      for (int kt = 0; kt < 4; ++kt)
        #pragma unroll
        for (int hf = 0; hf < 2; ++hf)
          aK[kt][hf] = *(const s16x8*)&Kb[(kt * 16 + l16) * 64 + (((hf * 4 + quad) ^ rsw) * 8)];

      f32x4 S[2][4];
      __builtin_amdgcn_s_setprio(1);
      #pragma unroll
      for (int kt = 0; kt < 4; ++kt)
        #pragma unroll
        for (int s = 0; s < 2; ++s) {
          f32x4 z = {};
          z = MFMA16(aK[kt][0], bQ[s][0], z);
          S[s][kt] = MFMA16(aK[kt][1], bQ[s][1], z);
        }
      __builtin_amdgcn_s_setprio(0);

      if (masked) {
        #pragma unroll
        for (int s = 0; s < 2; ++s) {
          int q = q0w + s * 16 + l16;
          #pragma unroll
          for (int kt = 0; kt < 4; ++kt) {
            int key0 = j * 64 + kt * 16 + quad * 4;
            #pragma unroll
            for (int r = 0; r < 4; ++r)
              if (key0 + r > q) S[s][kt][r] = -1e30f;
          }
        }
      }

      s16x8 aV[4][2];
      #pragma unroll
      for (int s = 0; s < 2; ++s) {
        // softmax for this s-block
        float sum = 0.0f;
        #pragma unroll
        for (int kt = 0; kt < 4; ++kt) {
          #pragma unroll
          for (int r = 0; r < 4; ++r) {
            float e = fexp2(S[s][kt][r]);
            S[s][kt][r] = e;
            sum += e;
          }
        }
        sum += __shfl_xor(sum, 16);
        sum += __shfl_xor(sum, 32);
        l_run[s] += sum;
        // pack+write P into the single shared s-block buffer (XOR swizzled):
        // row l16 (128 B); 16B-group (2*kt + quad>>1) ^ (l16&7), off (quad&1)*8
        #pragma unroll
        for (int kt = 0; kt < 4; ++kt) {
          uint2 pw;
          pw.x = pk2bf(S[s][kt][0], S[s][kt][1]);
          pw.y = pk2bf(S[s][kt][2], S[s][kt][3]);
          *(uint2*)&PwB[l16 * 128 + (((2 * kt + (quad >> 1)) ^ rsw) * 16) + (quad & 1) * 8] = pw;
        }
        if (s == 0) {
          // aV loads issue here: V buffer ready; drains under s=0's P round-trip
          #pragma unroll
          for (int dt = 0; dt < 4; ++dt)
            #pragma unroll
            for (int hf = 0; hf < 2; ++hf)
              aV[dt][hf] = *(const s16x8*)&Vb[(dt * 16 + l16) * 64 + (((hf * 4 + quad) ^ rsw) * 8)];
        }
        // read bP for this s (same-wave DS ops are in-order)
        s16x8 bP0 = *(const s16x8*)&PwB[l16 * 128 + ((quad ^ rsw) * 16)];
        s16x8 bP1 = *(const s16x8*)&PwB[l16 * 128 + (((4 + quad) ^ rsw) * 16)];
        __builtin_amdgcn_s_setprio(1);
        #pragma unroll
        for (int dt = 0; dt < 4; ++dt) {
          O[s][dt] = MFMA16(aV[dt][0], bP0, O[s][dt]);
          O[s][dt] = MFMA16(aV[dt][1], bP1, O[s][dt]);
        }
        __builtin_amdgcn_s_setprio(0);
      }
    }

    __syncthreads();  // drains prefetch vmcnt + all LDS reads; flip dbuf
  }

  // ---- parity combine: O_tot = O_p0 + O_p1, l_tot likewise (exact) ----
  // Staging region dead; wq-pair uses K-slot wq (8 KB); Lsl in dead P region.
  if (wp == 1) {
    float* Lsl = (float*)(smem + 65536 + wq * 512);
    Lsl[lane]      = l_run[0];
    Lsl[64 + lane] = l_run[1];
    f32x4* slot = (f32x4*)smem + wq * 512;
    #pragma unroll
    for (int s = 0; s < 2; ++s)
      #pragma unroll
      for (int dt = 0; dt < 4; ++dt)
        slot[(s * 4 + dt) * 64 + lane] = O[s][dt];
  }
  __syncthreads();
  if (wp == 0) {
    const float* Lsl = (const float*)(smem + 65536 + wq * 512);
    const f32x4* slot = (const f32x4*)smem + wq * 512;
    #pragma unroll
    for (int s = 0; s < 2; ++s) {
      float l_tot = l_run[s] + Lsl[s * 64 + lane];
      float inv = __builtin_amdgcn_rcpf(l_tot);
      int q = q0w + s * 16 + l16;
      #pragma unroll
      for (int dt = 0; dt < 4; ++dt) {
        f32x4 o = O[s][dt] + slot[(s * 4 + dt) * 64 + lane];
        uint2 ow;
        ow.x = pk2bf(o[0] * inv, o[1] * inv);
        ow.y = pk2bf(o[2] * inv, o[3] * inv);
        *(uint2*)&AO[(size_t)(b * 2048 + q) * 1024 + h * 64 + dt * 16 + quad * 4] = ow;
      }
    }
  }
}

// ---------------- launcher ----------------
extern "C" void kernel_launch(void* const* d_in, const int* in_sizes, int n_in,
                              void* d_out, int out_size, void* d_ws, size_t ws_size,
                              hipStream_t stream) {
  const float* x      = (const float*)d_in[0];
  const float* norm_w = (const float*)d_in[1];
  const float* w_qkv  = (const float*)d_in[2];
  const float* w_out  = (const float*)d_in[3];
  float* out = (float*)d_out;

  u16* ws     = (u16*)d_ws;
  u16* wqkv_b = ws;                      // 3 145 728
  u16* wout_b = wqkv_b + 3145728;        // 1 048 576
  u16* h_b    = wout_b + 1048576;        // 4 194 304
  u16* Qr     = h_b + 4194304 + 12582912;  // 4 194 304
  u16* Kr     = Qr + 4194304;            // 4 194 304
  u16* Vt     = Kr + 4194304;            // 4 194 304
  u16* AO     = Vt + 4194304;            // 4 194 304

  prep_kernel<<<8192, 256, 0, stream>>>(x, norm_w, w_qkv, w_out, h_b, wqkv_b, wout_b);
  gemm256<<<192, 512, 0, stream>>>(h_b, wqkv_b, Qr, Kr, Vt);
  attn_kernel<<<512, 512, 0, stream>>>(Qr, Kr, Vt, AO);
  gemm_bt<1><<<dim3(8, 32), 256, 0, stream>>>(AO, wout_b, nullptr, out, x,
                                              4096, 1024, 1024);
}

// Round 16
// 175.086 us; speedup vs baseline: 1.0604x; 1.0604x over previous
//
#include <hip/hip_runtime.h>
#include <math.h>

typedef unsigned short u16;
typedef unsigned int u32;
typedef __attribute__((ext_vector_type(4))) float f32x4;
typedef __attribute__((ext_vector_type(8))) short s16x8;

#define GLL16(g, l) __builtin_amdgcn_global_load_lds( \
    (const __attribute__((address_space(1))) void*)(g), \
    (__attribute__((address_space(3))) void*)(l), 16, 0, 0)

#define MFMA16(a, b, c) __builtin_amdgcn_mfma_f32_16x16x32_bf16(a, b, c, 0, 0, 0)

__device__ __forceinline__ u16 f2bf(float f) {
  union { float f; u32 u; } v; v.f = f;
  u32 r = v.u + 0x7FFFu + ((v.u >> 16) & 1u);
  return (u16)(r >> 16);
}
__device__ __forceinline__ float bf2f(u16 h) {
  union { u32 u; float f; } v; v.u = ((u32)h) << 16;
  return v.f;
}
// pack two floats to bf16x2 (round-half-up) in one v_perm
__device__ __forceinline__ u32 pk2bf(float lo, float hi) {
  union { float f; u32 u; } a, b; a.f = lo; b.f = hi;
  return __builtin_amdgcn_perm(b.u + 0x8000u, a.u + 0x8000u, 0x07060302u);
}
__device__ __forceinline__ float fexp2(float x) {
#if __has_builtin(__builtin_amdgcn_exp2f)
  return __builtin_amdgcn_exp2f(x);
#else
  return exp2f(x);
#endif
}
// hardware sin/cos on pre-reduced revolutions (r in [0,1)); register-only,
// no library call, no scratch (R9 post-mortem: ocml sincosf spilled ~200 MB).
__device__ __forceinline__ float fsin_rev(float r) {
#if __has_builtin(__builtin_amdgcn_sinf)
  return __builtin_amdgcn_sinf(r);
#else
  return __sinf(r * 6.283185307179586f);
#endif
}
__device__ __forceinline__ float fcos_rev(float r) {
#if __has_builtin(__builtin_amdgcn_cosf)
  return __builtin_amdgcn_cosf(r);
#else
  return __cosf(r * 6.283185307179586f);
#endif
}

// ---------------- fused prep: rmsnorm + both weight casts (1 launch) ----------
__global__ __launch_bounds__(256) void prep_kernel(const float* __restrict__ x,
                                                   const float* __restrict__ wgt,
                                                   const float* __restrict__ w_qkv,
                                                   const float* __restrict__ w_out,
                                                   u16* __restrict__ h,
                                                   u16* __restrict__ wqkv_b,
                                                   u16* __restrict__ wout_b) {
  __shared__ float red[4];
  const int bid = blockIdx.x, tid = threadIdx.x;
  if (bid < 4096) {
    // RMSNorm row
    const int row = bid;
    const float4 v = *(const float4*)&x[(size_t)row * 1024 + tid * 4];
    float ss = v.x * v.x + v.y * v.y + v.z * v.z + v.w * v.w;
    ss += __shfl_xor(ss, 1);  ss += __shfl_xor(ss, 2);  ss += __shfl_xor(ss, 4);
    ss += __shfl_xor(ss, 8);  ss += __shfl_xor(ss, 16); ss += __shfl_xor(ss, 32);
    if ((tid & 63) == 0) red[tid >> 6] = ss;
    __syncthreads();
    const float tot = red[0] + red[1] + red[2] + red[3];
    const float s = rsqrtf(tot * (1.0f / 1024.0f) + 1e-6f);
    const float4 g = *(const float4*)&wgt[tid * 4];
    uint2 o;
    o.x = (u32)f2bf(v.x * s * g.x) | ((u32)f2bf(v.y * s * g.y) << 16);
    o.y = (u32)f2bf(v.z * s * g.z) | ((u32)f2bf(v.w * s * g.w) << 16);
    *(uint2*)&h[(size_t)row * 1024 + tid * 4] = o;
  } else if (bid < 7168) {
    int i = (bid - 4096) * 256 + tid;          // 786432 float4 of w_qkv
    float4 v = ((const float4*)w_qkv)[i];
    uint2 o;
    o.x = (u32)f2bf(v.x) | ((u32)f2bf(v.y) << 16);
    o.y = (u32)f2bf(v.z) | ((u32)f2bf(v.w) << 16);
    ((uint2*)wqkv_b)[i] = o;
  } else {
    int i = (bid - 7168) * 256 + tid;          // 262144 float4 of w_out
    float4 v = ((const float4*)w_out)[i];
    uint2 o;
    o.x = (u32)f2bf(v.x) | ((u32)f2bf(v.y) << 16);
    o.y = (u32)f2bf(v.z) | ((u32)f2bf(v.w) << 16);
    ((uint2*)wout_b)[i] = o;
  }
}

// ---------------- GEMM 128^2 (kept for out-proj): C = A * Bt^T ----------------
template <int EPI>  // 0: write bf16 C. 1: write fp32 C = acc + resid
__global__ __launch_bounds__(256) void gemm_bt(const u16* __restrict__ A,
                                               const u16* __restrict__ Bt,
                                               u16* __restrict__ Cb,
                                               float* __restrict__ Cf,
                                               const float* __restrict__ resid,
                                               int M, int N, int K) {
  __shared__ __attribute__((aligned(16))) u16 As[128 * 32];
  __shared__ __attribute__((aligned(16))) u16 Bs[128 * 32];
  const int tid = threadIdx.x;
  const int w = tid >> 6, lane = tid & 63;
  const int quad = lane >> 4, l16 = lane & 15;
  const int gm0 = blockIdx.y * 128, gn0 = blockIdx.x * 128;
  const int wm = (w & 1) * 64, wn = (w >> 1) * 64;

  f32x4 acc[4][4] = {};

  for (int k0 = 0; k0 < K; k0 += 32) {
    __syncthreads();
    if (w < 2) {
      #pragma unroll
      for (int i = 0; i < 4; ++i) {
        int sb = (w * 4 + i) * 64;
        int slot = sb + lane;
        int m = slot >> 2, c = (slot & 3) ^ (m & 3);
        GLL16(A + (size_t)(gm0 + m) * K + k0 + c * 8, &As[sb * 8]);
      }
    } else {
      #pragma unroll
      for (int i = 0; i < 4; ++i) {
        int sb = ((w - 2) * 4 + i) * 64;
        int slot = sb + lane;
        int n = slot >> 2, c = (slot & 3) ^ (n & 3);
        GLL16(Bt + (size_t)(gn0 + n) * K + k0 + c * 8, &Bs[sb * 8]);
      }
    }
    __syncthreads();
    s16x8 aF[4], bF[4];
    #pragma unroll
    for (int i = 0; i < 4; ++i) {
      int m = wm + i * 16 + l16;
      aF[i] = *(const s16x8*)&As[(m * 4 + (quad ^ (m & 3))) * 8];
    }
    #pragma unroll
    for (int j = 0; j < 4; ++j) {
      int n = wn + j * 16 + l16;
      bF[j] = *(const s16x8*)&Bs[(n * 4 + (quad ^ (n & 3))) * 8];
    }
    #pragma unroll
    for (int i = 0; i < 4; ++i)
      #pragma unroll
      for (int j = 0; j < 4; ++j)
        acc[i][j] = MFMA16(aF[i], bF[j], acc[i][j]);
  }

  #pragma unroll
  for (int i = 0; i < 4; ++i) {
    int row0 = gm0 + wm + i * 16 + quad * 4;
    #pragma unroll
    for (int j = 0; j < 4; ++j) {
      int col = gn0 + wn + j * 16 + l16;
      #pragma unroll
      for (int r = 0; r < 4; ++r) {
        size_t idx = (size_t)(row0 + r) * N + col;
        if (EPI == 0) Cb[idx] = f2bf(acc[i][j][r]);
        else          Cf[idx] = acc[i][j][r] + resid[idx];
      }
    }
  }
}

// ---------------- GEMM 256^2 v3b: QKV matmul + fused RoPE/V-transpose ---------
// (R11/R14 best configuration, passing at ~43 us incl. fused epilogue)
__global__ __launch_bounds__(512, 2) void gemm256(const u16* __restrict__ A,
                                                  const u16* __restrict__ Bt,
                                                  u16* __restrict__ Qr,
                                                  u16* __restrict__ Kr,
                                                  u16* __restrict__ Vt) {
  __shared__ __attribute__((aligned(16))) char smem[131072];
  const int tid = threadIdx.x;
  const int w = tid >> 6, lane = tid & 63;
  const int quad = lane >> 4, l16 = lane & 15;
  const int wr = w >> 2, wc = w & 3;
  const int rsw = l16 & 7;
  const int id = blockIdx.x;
  const int sw = (id & 7) * 24 + (id >> 3);    // XCD swizzle, 192 = 8 x 24
  const int by = sw / 12, bx = sw - by * 12;
  const int gm0 = by * 256, gn0 = bx * 256;
  const int scg = (lane & 7) ^ (lane >> 3);    // pre-swizzled src col-group

  // part: 0=A half0, 1=A half1, 2=B half0, 3=B half1 (half = 128 rows)
  auto STAGE_HALF = [&](int kt, int part) {
    const int sb = (kt & 1) * 65536 + (part >> 1) * 32768 + (part & 1) * 16384;
    const u16* src = (part >> 1) ? Bt : A;
    const int g0 = ((part >> 1) ? gn0 : gm0) + (part & 1) * 128;
    const int k0 = kt * 64;
    #pragma unroll
    for (int q = 0; q < 2; ++q) {
      int r = q * 64 + (tid >> 3);
      GLL16(src + (size_t)(g0 + r) * 1024 + k0 + scg * 8,
            smem + sb + q * 8192 + w * 1024);
    }
  };

  f32x4 acc[8][4] = {};

  // prologue: A(0), B(0), B(1).  vmcnt(4): A(0)+B(0) landed, B(1) in flight.
  STAGE_HALF(0, 0); STAGE_HALF(0, 1);
  STAGE_HALF(0, 2); STAGE_HALF(0, 3);
  STAGE_HALF(1, 2); STAGE_HALF(1, 3);
  asm volatile("s_waitcnt vmcnt(4)" ::: "memory");
  __builtin_amdgcn_s_barrier();

  for (int kt = 0; kt < 16; ++kt) {
    const char* Ab = smem + (kt & 1) * 65536;
    const char* Bb = Ab + 32768;
    const int arow = wr * 128 + l16;            // (row&7)==rsw for all frags
    const int brow = wc * 64 + l16;
    s16x8 aA[4][2], bB[4][2];

    // reads: A row-group 0 (8 x b128) + all B (8 x b128)
    #pragma unroll
    for (int fi = 0; fi < 4; ++fi) {
      const char* p = Ab + (arow + fi * 16) * 128;
      aA[fi][0] = *(const s16x8*)(p + ((quad ^ rsw) * 16));
      aA[fi][1] = *(const s16x8*)(p + (((4 + quad) ^ rsw) * 16));
    }
    #pragma unroll
    for (int fj = 0; fj < 4; ++fj) {
      const char* p = Bb + (brow + fj * 16) * 128;
      bB[fj][0] = *(const s16x8*)(p + ((quad ^ rsw) * 16));
      bB[fj][1] = *(const s16x8*)(p + (((4 + quad) ^ rsw) * 16));
    }

    // stage A(kt+1) into the other buffer (its previous content consumed @ kt-1)
    if (kt < 15) { STAGE_HALF(kt + 1, 0); STAGE_HALF(kt + 1, 1); }

    // MFMA row-group 0 x all cols (32) - compiler interleaves lgkmcnt waits
    __builtin_amdgcn_s_setprio(1);
    #pragma unroll
    for (int fi = 0; fi < 4; ++fi)
      #pragma unroll
      for (int fj = 0; fj < 4; ++fj) {
        acc[fi][fj] = MFMA16(aA[fi][0], bB[fj][0], acc[fi][fj]);
        acc[fi][fj] = MFMA16(aA[fi][1], bB[fj][1], acc[fi][fj]);
      }
    __builtin_amdgcn_s_setprio(0);

    // reads: A row-group 1 (8 x b128) - drains under rg0 MFMA execution
    #pragma unroll
    for (int fi = 0; fi < 4; ++fi) {
      const char* p = Ab + (arow + (4 + fi) * 16) * 128;
      aA[fi][0] = *(const s16x8*)(p + ((quad ^ rsw) * 16));
      aA[fi][1] = *(const s16x8*)(p + (((4 + quad) ^ rsw) * 16));
    }

    // MFMA row-group 1 x all cols (32)
    __builtin_amdgcn_s_setprio(1);
    #pragma unroll
    for (int fi = 0; fi < 4; ++fi)
      #pragma unroll
      for (int fj = 0; fj < 4; ++fj) {
        acc[4 + fi][fj] = MFMA16(aA[fi][0], bB[fj][0], acc[4 + fi][fj]);
        acc[4 + fi][fj] = MFMA16(aA[fi][1], bB[fj][1], acc[4 + fi][fj]);
      }
    __builtin_amdgcn_s_setprio(0);

    // all waves' reads of buf[kt&1] complete (consumed by MFMAs above)
    __builtin_amdgcn_s_barrier();

    // stage B(kt+2) into buf[kt&1] B-region (now dead)
    if (kt < 14) {
      STAGE_HALF(kt + 2, 2); STAGE_HALF(kt + 2, 3);
      asm volatile("s_waitcnt vmcnt(4)" ::: "memory");   // A(kt+1),B(kt+1) landed
    } else if (kt == 14) {
      asm volatile("s_waitcnt vmcnt(0)" ::: "memory");   // A(15) landed
    }
    __builtin_amdgcn_s_barrier();
  }

  // ---- fused epilogue: RoPE (Q/K) or transpose (V), direct to final layout --
  const int bb = gm0 >> 11;                    // batch (rows are 2048-aligned blocks)
  const int tt0 = (gm0 & 2047) + wr * 128;     // this wave's first token
  if (bx < 8) {
    const bool isQ = (bx < 4);
    const int h = ((bx & 3) << 2) + wc;        // head index 0..15
    const size_t obase = (size_t)(bb * 16 + h) * (2048 * 64);
    u16* dst = isQ ? Qr : Kr;
    const float SC = isQ ? 0.125f * 1.4426950408889634f : 1.0f;
    #pragma unroll
    for (int fj = 0; fj < 2; ++fj) {
      const int jj = fj * 16 + l16;            // rotation pair index 0..31
      // invf/(2*pi): angle in revolutions, fract-reduce, hardware sin/cos
      const float invf_rev = fexp2(-(float)jj * (13.287712379549449f / 32.0f)) *
                             0.15915494309189535f;
      #pragma unroll
      for (int g = 0; g < 8; ++g) {
        #pragma unroll
        for (int r = 0; r < 4; ++r) {
          const int t = tt0 + g * 16 + quad * 4 + r;
          const float rev = (float)t * invf_rev;
          const float fr = rev - floorf(rev);
          const float sn = fsin_rev(fr), cs = fcos_rev(fr);
          const float q1 = acc[g][fj][r], q2 = acc[g][2 + fj][r];
          dst[obase + (size_t)t * 64 + jj]      = f2bf((q1 * cs - q2 * sn) * SC);
          dst[obase + (size_t)t * 64 + jj + 32] = f2bf((q2 * cs + q1 * sn) * SC);
        }
      }
    }
  } else {
    // V: per-wave head, transpose 256x64 through LDS (32 KB per head, 4 heads
    // = exactly the 128 KB smem, dead after the K-loop's final barrier).
    const int h = ((bx - 8) << 2) + wc;
    const size_t obase = (size_t)(bb * 16 + h) * 64;   // Vt row base (bh*64)
    u16* Vl = (u16*)smem + wc * 16384;
    #pragma unroll
    for (int g = 0; g < 8; ++g)
      #pragma unroll
      for (int fj = 0; fj < 4; ++fj) {
        const int d = fj * 16 + l16;
        #pragma unroll
        for (int r = 0; r < 4; ++r) {
          const int tl = wr * 128 + g * 16 + quad * 4 + r;
          Vl[tl * 64 + (d ^ (((tl >> 3) & 7) << 3))] = f2bf(acc[g][fj][r]);
        }
      }
    __syncthreads();   // uniform within block (bx is block-constant)
    const int c = lane & 7, lg = lane >> 3;
    const int tb = gm0 & 2047;
    #pragma unroll
    for (int c32 = wr * 2; c32 < wr * 2 + 2; ++c32)
      #pragma unroll
      for (int dp = 0; dp < 8; ++dp) {
        const int d = dp * 8 + lg;
        const u16* col = Vl + (c32 * 64 + c * 8) * 64 + (d ^ (c << 3));
        u16 tmp[8];
        #pragma unroll
        for (int k = 0; k < 8; ++k) tmp[k] = col[k * 64];
        *(uint4*)&Vt[(obase + d) * 2048 + tb + c32 * 64 + c * 8] = *(uint4*)tmp;
      }
  }
}

// ---------------- Flash attention v8c (session best: ~39.5 us) ---------------
// Final configuration. Tested alternatives and outcomes:
//   v9  (4-wave blocks, 2-3 blocks/CU, no prefetch): 42.5 us (-3)
//   v10 ((512,4) clause -> 64 VGPR spill):          143 us  (-103)
//   v10b (80 KB LDS, natural alloc): only 1 block/CU fit (2x80K = exactly
//        the 160 KB pool doesn't co-schedule) + P-serialization: 47.4 us (-8)
// Min-waves clauses force the allocator below the ~100-VGPR working set;
// plain (512) + 100 KB LDS (1 block/CU) is the verified optimum.
__global__ __launch_bounds__(512) void attn_kernel(const u16* __restrict__ Qr,
                                                   const u16* __restrict__ Kr,
                                                   const u16* __restrict__ Vt,
                                                   u16* __restrict__ AO) {
  // [0,32K): K[par*2+d][8192]  [32K,64K): V[par*2+d][8192]  [64K,100K): P[8][4608]
  __shared__ __attribute__((aligned(16))) char smem[102400];
  const int tid = threadIdx.x;
  const int w = tid >> 6, lane = tid & 63;
  const int wq = w & 3, wp = w >> 2;          // compute roles: q-quarter, j-parity
  const int quad = lane >> 4, l16 = lane & 15;
  const int id = blockIdx.x;
  const int bh = id & 31;                     // id%8 = bh%8 -> per-bh XCD affinity
  const int c  = id >> 5;                     // pair index 0..7
  const int b = bh >> 4, h = bh & 15;
  const size_t qkb = (size_t)bh * (2048 * 64);
  const size_t vtb = (size_t)bh * (64 * 2048);
  u16* Pw = (u16*)(smem + 65536 + w * 4608);

  const int srow = lane >> 3;                 // row within an 8-row issue
  const int scg  = (lane & 7) ^ srow;         // pre-swizzled 16B col group
  const int smat = w & 1, stp = (w >> 1) & 1, shalf = (w >> 2) & 1;

  auto STAGE = [&](int j0, int d) {
    const int jn = j0 + stp;
    if (smat == 0) {
      #pragma unroll
      for (int ii = 0; ii < 4; ++ii) {
        int i = shalf * 4 + ii;               // 8-row block 0..7
        GLL16(Kr + qkb + (size_t)(jn * 64 + i * 8 + srow) * 64 + scg * 8,
              smem + (stp * 2 + d) * 8192 + i * 1024);
      }
    } else {
      #pragma unroll
      for (int ii = 0; ii < 4; ++ii) {
        int i = shalf * 4 + ii;               // 8 d-rows each
        GLL16(Vt + vtb + (size_t)(i * 8 + srow) * 2048 + jn * 64 + scg * 8,
              smem + 32768 + (stp * 2 + d) * 8192 + i * 1024);
      }
    }
  };

  for (int t = 0; t < 2; ++t) {
    const int qblk = t ? (15 - c) : c;
    const int q0w = qblk * 128 + wq * 32;     // this wave's 32 q-rows
    const int steps = qblk + 1;               // j-tiles = 2*steps (always even)

    s16x8 bQ[2][2];
    #pragma unroll
    for (int s = 0; s < 2; ++s)
      #pragma unroll
      for (int hf = 0; hf < 2; ++hf)
        bQ[s][hf] = *(const s16x8*)&Qr[qkb + (size_t)(q0w + s * 16 + l16) * 64 + hf * 32 + quad * 8];

    f32x4 O[2][4] = {};
    float l_run[2] = {0.0f, 0.0f};

    STAGE(0, 0);
    __syncthreads();

    for (int st = 0; st < steps; ++st) {
      const int cur = st & 1;
      if (st + 1 < steps) STAGE(2 * st + 2, cur ^ 1);

      const int j = 2 * st + wp;
      if (j * 64 <= q0w + 31) {
        const u16* Kb = (const u16*)(smem + (wp * 2 + cur) * 8192);
        const u16* Vb = (const u16*)(smem + 32768 + (wp * 2 + cur) * 8192);
        const bool masked = (j * 64 + 63 > q0w);
        const int rsw = (l16 & 7);

        s16x8 aK[4][2];
        #pragma unroll
        for (int kt = 0; kt < 4; ++kt)
          #pragma unroll
          for (int hf = 0; hf < 2; ++hf)
            aK[kt][hf] = *(const s16x8*)&Kb[(kt * 16 + l16) * 64 + (((hf * 4 + quad) ^ rsw) * 8)];

        f32x4 S[2][4];
        __builtin_amdgcn_s_setprio(1);
        #pragma unroll
        for (int kt = 0; kt < 4; ++kt)
          #pragma unroll
          for (int s = 0; s < 2; ++s) {
            f32x4 z = {};
            z = MFMA16(aK[kt][0], bQ[s][0], z);
            S[s][kt] = MFMA16(aK[kt][1], bQ[s][1], z);
          }
        __builtin_amdgcn_s_setprio(0);

        if (masked) {
          #pragma unroll
          for (int s = 0; s < 2; ++s) {
            int q = q0w + s * 16 + l16;
            #pragma unroll
            for (int kt = 0; kt < 4; ++kt) {
              int key0 = j * 64 + kt * 16 + quad * 4;
              #pragma unroll
              for (int r = 0; r < 4; ++r)
                if (key0 + r > q) S[s][kt][r] = -1e30f;
            }
          }
        }

        #pragma unroll
        for (int s = 0; s < 2; ++s) {
          float sum = 0.0f;
          #pragma unroll
          for (int kt = 0; kt < 4; ++kt) {
            #pragma unroll
            for (int r = 0; r < 4; ++r) {
              float e = fexp2(S[s][kt][r]);
              S[s][kt][r] = e;
              sum += e;
            }
          }
          sum += __shfl_xor(sum, 16);
          sum += __shfl_xor(sum, 32);
          l_run[s] += sum;
          #pragma unroll
          for (int kt = 0; kt < 4; ++kt) {
            uint2 pw;
            pw.x = pk2bf(S[s][kt][0], S[s][kt][1]);
            pw.y = pk2bf(S[s][kt][2], S[s][kt][3]);
            *(uint2*)&Pw[s * 1152 + l16 * 72 + kt * 16 + quad * 4] = pw;
          }
        }

        s16x8 bP[2][2];
        #pragma unroll
        for (int s = 0; s < 2; ++s) {
          bP[s][0] = *(const s16x8*)&Pw[s * 1152 + l16 * 72 + quad * 8];
          bP[s][1] = *(const s16x8*)&Pw[s * 1152 + l16 * 72 + 32 + quad * 8];
        }
        s16x8 aV[4][2];
        #pragma unroll
        for (int dt = 0; dt < 4; ++dt)
          #pragma unroll
          for (int hf = 0; hf < 2; ++hf)
            aV[dt][hf] = *(const s16x8*)&Vb[(dt * 16 + l16) * 64 + (((hf * 4 + quad) ^ rsw) * 8)];

        __builtin_amdgcn_s_setprio(1);
        #pragma unroll
        for (int dt = 0; dt < 4; ++dt)
          #pragma unroll
          for (int s = 0; s < 2; ++s) {
            O[s][dt] = MFMA16(aV[dt][0], bP[s][0], O[s][dt]);
            O[s][dt] = MFMA16(aV[dt][1], bP[s][1], O[s][dt]);
          }
        __builtin_amdgcn_s_setprio(0);
      }

      __syncthreads();
    }

    // ---- parity combine (exact) ----
    if (wp == 1) {
      float* Lsl = (float*)(smem + 65536 + wq * 512);
      Lsl[lane]      = l_run[0];
      Lsl[64 + lane] = l_run[1];
      f32x4* slot = (f32x4*)smem + wq * 512;
      #pragma unroll
      for (int s = 0; s < 2; ++s)
        #pragma unroll
        for (int dt = 0; dt < 4; ++dt)
          slot[(s * 4 + dt) * 64 + lane] = O[s][dt];
    }
    __syncthreads();
    if (wp == 0) {
      const float* Lsl = (const float*)(smem + 65536 + wq * 512);
      const f32x4* slot = (const f32x4*)smem + wq * 512;
      #pragma unroll
      for (int s = 0; s < 2; ++s) {
        float l_tot = l_run[s] + Lsl[s * 64 + lane];
        float inv = __builtin_amdgcn_rcpf(l_tot);
        int q = q0w + s * 16 + l16;
        #pragma unroll
        for (int dt = 0; dt < 4; ++dt) {
          f32x4 o = O[s][dt] + slot[(s * 4 + dt) * 64 + lane];
          uint2 ow;
          ow.x = pk2bf(o[0] * inv, o[1] * inv);
          ow.y = pk2bf(o[2] * inv, o[3] * inv);
          *(uint2*)&AO[(size_t)(b * 2048 + q) * 1024 + h * 64 + dt * 16 + quad * 4] = ow;
        }
      }
    }
    __syncthreads();
  }
}

// ---------------- launcher ----------------
extern "C" void kernel_launch(void* const* d_in, const int* in_sizes, int n_in,
                              void* d_out, int out_size, void* d_ws, size_t ws_size,
                              hipStream_t stream) {
  const float* x      = (const float*)d_in[0];
  const float* norm_w = (const float*)d_in[1];
  const float* w_qkv  = (const float*)d_in[2];
  const float* w_out  = (const float*)d_in[3];
  float* out = (float*)d_out;

  u16* ws     = (u16*)d_ws;
  u16* wqkv_b = ws;                      // 3 145 728
  u16* wout_b = wqkv_b + 3145728;        // 1 048 576
  u16* h_b    = wout_b + 1048576;        // 4 194 304
  u16* Qr     = h_b + 4194304 + 12582912;  // 4 194 304
  u16* Kr     = Qr + 4194304;            // 4 194 304
  u16* Vt     = Kr + 4194304;            // 4 194 304
  u16* AO     = Vt + 4194304;            // 4 194 304

  prep_kernel<<<8192, 256, 0, stream>>>(x, norm_w, w_qkv, w_out, h_b, wqkv_b, wout_b);
  gemm256<<<192, 512, 0, stream>>>(h_b, wqkv_b, Qr, Kr, Vt);
  attn_kernel<<<256, 512, 0, stream>>>(Qr, Kr, Vt, AO);
  gemm_bt<1><<<dim3(8, 32), 256, 0, stream>>>(AO, wout_b, nullptr, out, x,
                                              4096, 1024, 1024);
}